// Round 1
// baseline (594.995 us; speedup 1.0000x reference)
//
#include <hip/hip_runtime.h>
#include <math.h>

#define B_ 128
#define E_ 512
#define C_ 128
#define H_ 8
#define D_ 64

__device__ __forceinline__ float selu_f(float x) {
    const float alpha = 1.6732632423543772f;
    const float scale = 1.0507009873554805f;
    return x > 0.0f ? scale * x : scale * alpha * expm1f(x);
}

// ---------------------------------------------------------------------------
// Detect whether knn_mask was passed as 1-byte bools or 4-byte ints.
// First 16384 bytes: bool layout -> 21*128 = 2688 nonzero bytes;
// int32 layout -> first 32 rows only -> 21*32 = 672 nonzero bytes.
// ---------------------------------------------------------------------------
__global__ void detect_mask_kernel(const unsigned char* __restrict__ m,
                                   int* __restrict__ flag) {
    __shared__ int cnt;
    if (threadIdx.x == 0) cnt = 0;
    __syncthreads();
    int local = 0;
    for (int i = threadIdx.x; i < C_ * C_; i += blockDim.x) local += (m[i] != 0);
    atomicAdd(&cnt, local);
    __syncthreads();
    if (threadIdx.x == 0) *flag = (cnt > 1600) ? 1 : 0;  // 1 = bool bytes, 0 = int32
}

// ---------------------------------------------------------------------------
// comb[h][i][j] = mask ? attn_bias[i][j] + (dir_bias - rowmean) : -inf
// dir_bias[h,i,j] = 0.5*(dm[i,j]*dvn[h,j] - dm[j,i]*dvn[h,i]),
// dm = mean over xyz of displacement, dvn = row-normalized dir_vec.
// One block per (i, h); 128 threads over j.
// ---------------------------------------------------------------------------
__global__ __launch_bounds__(128) void bias_prep_kernel(
    const float* __restrict__ dir_vec, const float* __restrict__ attn_bias,
    const float* __restrict__ disp, const unsigned char* __restrict__ maskb,
    const int* __restrict__ flag, float* __restrict__ comb)
{
    const int i = blockIdx.x, h = blockIdx.y, j = threadIdx.x;
    __shared__ float red[128];

    float dv = dir_vec[h * C_ + j];
    red[j] = dv * dv;
    __syncthreads();
    for (int s = 64; s > 0; s >>= 1) {
        if (j < s) red[j] += red[j + s];
        __syncthreads();
    }
    const float nrm = fmaxf(sqrtf(red[0]), 1e-12f);
    __syncthreads();

    const float dvn_j = dir_vec[h * C_ + j] / nrm;
    const float dvn_i = dir_vec[h * C_ + i] / nrm;
    const float third = 1.0f / 3.0f;
    const float dm_ij = (disp[(i * C_ + j) * 3 + 0] + disp[(i * C_ + j) * 3 + 1] +
                         disp[(i * C_ + j) * 3 + 2]) * third;
    const float dm_ji = (disp[(j * C_ + i) * 3 + 0] + disp[(j * C_ + i) * 3 + 1] +
                         disp[(j * C_ + i) * 3 + 2]) * third;
    const float db = 0.5f * (dm_ij * dvn_j - dm_ji * dvn_i);

    red[j] = db;
    __syncthreads();
    for (int s = 64; s > 0; s >>= 1) {
        if (j < s) red[j] += red[j + s];
        __syncthreads();
    }
    const float rowmean = red[0] * (1.0f / 128.0f);

    const bool mk = (*flag) ? (maskb[i * C_ + j] != 0)
                            : (((const int*)maskb)[i * C_ + j] != 0);
    comb[((size_t)h * C_ + i) * C_ + j] =
        mk ? (attn_bias[i * C_ + j] + db - rowmean) : -INFINITY;
}

// ---------------------------------------------------------------------------
// out[p][b][o][c] = selu(sum_e W_p[o][e] * in[b][e][c])
// Block: 64 o-rows x 128 c-cols for one (b, p). 256 threads, 8x4 micro-tile.
// ---------------------------------------------------------------------------
__global__ __launch_bounds__(256) void proj_gemm_kernel(
    const float* __restrict__ W0, const float* __restrict__ W1,
    const float* __restrict__ W2, const float* __restrict__ in,
    float* __restrict__ out, size_t out_stride)
{
    const int p = blockIdx.z;
    const float* __restrict__ W = (p == 0) ? W0 : (p == 1) ? W1 : W2;
    float* __restrict__ o = out + (size_t)p * out_stride;

    const int b = blockIdx.y;
    const int o0 = blockIdx.x * 64;

    __shared__ float Ws[32][68];   // [kk][o], padded for 16B-aligned b128 reads
    __shared__ float Xs[32][128];  // [kk][c]

    const int tid = threadIdx.x;
    const int tx = tid & 31;   // c-group: c = tx*4 + [0..4)
    const int ty = tid >> 5;   // o-group: o = o0 + ty*8 + [0..8)

    const float* __restrict__ inb = in + (size_t)b * E_ * C_;

    float acc[8][4];
#pragma unroll
    for (int i = 0; i < 8; ++i)
#pragma unroll
        for (int jj = 0; jj < 4; ++jj) acc[i][jj] = 0.0f;

    for (int k0 = 0; k0 < E_; k0 += 32) {
        // W tile 64x32 -> transposed into Ws[kk][o]
#pragma unroll
        for (int r = 0; r < 2; ++r) {
            const int idx = tid + r * 256;        // 0..511
            const int row = idx >> 3, f4 = idx & 7;
            const float4 w4 = *(const float4*)&W[(size_t)(o0 + row) * E_ + k0 + f4 * 4];
            Ws[f4 * 4 + 0][row] = w4.x;
            Ws[f4 * 4 + 1][row] = w4.y;
            Ws[f4 * 4 + 2][row] = w4.z;
            Ws[f4 * 4 + 3][row] = w4.w;
        }
        // X tile 32x128 (flat float4 copy)
#pragma unroll
        for (int r = 0; r < 4; ++r) {
            const int idx = tid + r * 256;        // 0..1023
            const int e = idx >> 5, c4 = idx & 31;
            *(float4*)&Xs[e][c4 * 4] =
                *(const float4*)&inb[(size_t)(k0 + e) * C_ + c4 * 4];
        }
        __syncthreads();

#pragma unroll
        for (int kk = 0; kk < 32; ++kk) {
            float a[8];
#pragma unroll
            for (int i = 0; i < 8; ++i) a[i] = Ws[kk][ty * 8 + i];
            const float4 xv = *(float4*)&Xs[kk][tx * 4];
#pragma unroll
            for (int i = 0; i < 8; ++i) {
                acc[i][0] += a[i] * xv.x;
                acc[i][1] += a[i] * xv.y;
                acc[i][2] += a[i] * xv.z;
                acc[i][3] += a[i] * xv.w;
            }
        }
        __syncthreads();
    }

#pragma unroll
    for (int i = 0; i < 8; ++i) {
        float4 o4;
        o4.x = selu_f(acc[i][0]);
        o4.y = selu_f(acc[i][1]);
        o4.z = selu_f(acc[i][2]);
        o4.w = selu_f(acc[i][3]);
        *(float4*)&o[((size_t)b * E_ + o0 + ty * 8 + i) * C_ + tx * 4] = o4;
    }
}

// ---------------------------------------------------------------------------
// Attention: one block per (b, h). scores = q^T k * 0.125 + comb (has -inf
// mask folded in), softmax over j, attn = p @ v^T. Writes attn over the q
// buffer region it consumed.
// ---------------------------------------------------------------------------
__global__ __launch_bounds__(256) void attn_kernel(
    const float* __restrict__ qkv, const float* __restrict__ comb,
    float* __restrict__ attn)
{
    const int b = blockIdx.x, h = blockIdx.y;
    __shared__ float qs[D_ * C_];      // 32 KB, reused for v in phase 2
    __shared__ float ks[D_ * C_];      // 32 KB
    __shared__ float ps[C_][129];      // ~64.5 KB, odd stride vs bank conflicts

    const int tid = threadIdx.x;
    const size_t base = ((size_t)b * E_ + h * D_) * C_;
    const float* __restrict__ qg = qkv + base;
    const float* __restrict__ kg = qkv + (size_t)B_ * E_ * C_ + base;
    const float* __restrict__ vg = qkv + 2 * (size_t)B_ * E_ * C_ + base;

#pragma unroll
    for (int r = 0; r < 8; ++r) {
        const int idx = (tid + r * 256) * 4;
        *(float4*)&qs[idx] = *(const float4*)&qg[idx];
        *(float4*)&ks[idx] = *(const float4*)&kg[idx];
    }
    __syncthreads();

    const int ti = tid >> 4, tj = tid & 15;
    const int i0 = ti * 8, j0 = tj * 8;

    float acc[8][8];
#pragma unroll
    for (int ii = 0; ii < 8; ++ii)
#pragma unroll
        for (int jj = 0; jj < 8; ++jj) acc[ii][jj] = 0.0f;

#pragma unroll 4
    for (int d = 0; d < D_; ++d) {
        float a0[8], b0[8];
        *(float4*)&a0[0] = *(float4*)&qs[d * C_ + i0];
        *(float4*)&a0[4] = *(float4*)&qs[d * C_ + i0 + 4];
        *(float4*)&b0[0] = *(float4*)&ks[d * C_ + j0];
        *(float4*)&b0[4] = *(float4*)&ks[d * C_ + j0 + 4];
#pragma unroll
        for (int ii = 0; ii < 8; ++ii)
#pragma unroll
            for (int jj = 0; jj < 8; ++jj) acc[ii][jj] += a0[ii] * b0[jj];
    }

    // bias + masked softmax (row groups of 16 lanes: ti fixed, tj 0..15)
    const float* __restrict__ cb = comb + (size_t)h * C_ * C_;
#pragma unroll
    for (int ii = 0; ii < 8; ++ii) {
        const int i = i0 + ii;
        float s[8];
        float m = -INFINITY;
#pragma unroll
        for (int jj = 0; jj < 8; ++jj) {
            s[jj] = acc[ii][jj] * 0.125f + cb[i * C_ + j0 + jj];
            m = fmaxf(m, s[jj]);
        }
#pragma unroll
        for (int off = 1; off < 16; off <<= 1) m = fmaxf(m, __shfl_xor(m, off));
        float sum = 0.0f;
#pragma unroll
        for (int jj = 0; jj < 8; ++jj) {
            s[jj] = __expf(s[jj] - m);
            sum += s[jj];
        }
#pragma unroll
        for (int off = 1; off < 16; off <<= 1) sum += __shfl_xor(sum, off);
        const float inv = 1.0f / sum;
#pragma unroll
        for (int jj = 0; jj < 8; ++jj) ps[i][j0 + jj] = s[jj] * inv;
    }
    __syncthreads();

    // stage v over qs
#pragma unroll
    for (int r = 0; r < 8; ++r) {
        const int idx = (tid + r * 256) * 4;
        *(float4*)&qs[idx] = *(const float4*)&vg[idx];
    }
    __syncthreads();

    // PV: attn[d][i] = sum_j p[i][j] * v[d][j]
    const int td = tid >> 5, tc = tid & 31;
    const int dd0 = td * 8, ic0 = tc * 4;
    float acc2[8][4];
#pragma unroll
    for (int dd = 0; dd < 8; ++dd)
#pragma unroll
        for (int ii = 0; ii < 4; ++ii) acc2[dd][ii] = 0.0f;

#pragma unroll 2
    for (int j = 0; j < C_; ++j) {
        float vv[8], pv[4];
#pragma unroll
        for (int dd = 0; dd < 8; ++dd) vv[dd] = qs[(dd0 + dd) * C_ + j];
#pragma unroll
        for (int ii = 0; ii < 4; ++ii) pv[ii] = ps[ic0 + ii][j];
#pragma unroll
        for (int dd = 0; dd < 8; ++dd)
#pragma unroll
            for (int ii = 0; ii < 4; ++ii) acc2[dd][ii] += vv[dd] * pv[ii];
    }

#pragma unroll
    for (int dd = 0; dd < 8; ++dd) {
        *(float4*)&attn[((size_t)b * E_ + h * D_ + dd0 + dd) * C_ + ic0] =
            *(float4*)&acc2[dd][0];
    }
}

// ---------------------------------------------------------------------------
extern "C" void kernel_launch(void* const* d_in, const int* in_sizes, int n_in,
                              void* d_out, int out_size, void* d_ws, size_t ws_size,
                              hipStream_t stream) {
    const float* x        = (const float*)d_in[0];
    const float* wq       = (const float*)d_in[1];
    const float* wk       = (const float*)d_in[2];
    const float* wv       = (const float*)d_in[3];
    const float* wo       = (const float*)d_in[4];
    const float* dir_vec  = (const float*)d_in[5];
    const float* attn_b   = (const float*)d_in[6];
    const float* disp     = (const float*)d_in[7];
    const unsigned char* knn = (const unsigned char*)d_in[8];
    float* out = (float*)d_out;

    const size_t BEC = (size_t)B_ * E_ * C_;
    char* ws = (char*)d_ws;
    float* qkv  = (float*)ws;                              // 3*BEC floats (96 MB)
    float* comb = (float*)(ws + 3 * BEC * sizeof(float));  // H*C*C floats
    int*   flag = (int*)(ws + 3 * BEC * sizeof(float) + (size_t)H_ * C_ * C_ * sizeof(float));

    detect_mask_kernel<<<1, 256, 0, stream>>>(knn, flag);
    bias_prep_kernel<<<dim3(C_, H_), 128, 0, stream>>>(dir_vec, attn_b, disp, knn,
                                                       flag, comb);
    // q, k, v projections (z selects weight + output slice)
    proj_gemm_kernel<<<dim3(E_ / 64, B_, 3), 256, 0, stream>>>(wq, wk, wv, x, qkv, BEC);
    // attention; writes attn over the q slice of qkv
    attn_kernel<<<dim3(B_, H_), 256, 0, stream>>>(qkv, comb, qkv);
    // output projection from attn (= q slice) -> d_out
    proj_gemm_kernel<<<dim3(E_ / 64, B_, 1), 256, 0, stream>>>(wo, wo, wo, qkv, out, 0);
}

// Round 2
// 283.618 us; speedup vs baseline: 2.0979x; 2.0979x over previous
//
#include <hip/hip_runtime.h>
#include <math.h>

#define B_ 128
#define E_ 512
#define C_ 128
#define H_ 8
#define D_ 64
#define BEC_ ((size_t)B_ * E_ * C_)

typedef __attribute__((ext_vector_type(8))) __bf16 bf16x8;
typedef __attribute__((ext_vector_type(4))) float f32x4;

__device__ __forceinline__ ushort f2bf(float f) {
    unsigned u = __float_as_uint(f);
    unsigned r = u + 0x7fffu + ((u >> 16) & 1u);
    return (ushort)(r >> 16);
}
__device__ __forceinline__ float bf2f(ushort h) {
    return __uint_as_float(((unsigned)h) << 16);
}
__device__ __forceinline__ float selu_f(float x) {
    const float alpha = 1.6732632423543772f;
    const float scale = 1.0507009873554805f;
    return x > 0.0f ? scale * x : scale * alpha * expm1f(x);
}
// async global->LDS, 16B per lane; LDS dest is wave-uniform base + lane*16
__device__ __forceinline__ void gll16(const void* g, void* l) {
    __builtin_amdgcn_global_load_lds(
        (const __attribute__((address_space(1))) void*)g,
        (__attribute__((address_space(3))) void*)l, 16, 0, 0);
}

// ---------------------------------------------------------------------------
// knn_mask dtype sniff (bool bytes -> 2688 nonzero in 16KB, int32 -> 672)
// ---------------------------------------------------------------------------
__global__ void detect_mask_kernel(const unsigned char* __restrict__ m,
                                   int* __restrict__ flag) {
    __shared__ int cnt;
    if (threadIdx.x == 0) cnt = 0;
    __syncthreads();
    int local = 0;
    for (int i = threadIdx.x; i < C_ * C_; i += blockDim.x) local += (m[i] != 0);
    atomicAdd(&cnt, local);
    __syncthreads();
    if (threadIdx.x == 0) *flag = (cnt > 1600) ? 1 : 0;
}

// ---------------------------------------------------------------------------
// comb[h][i][j] = mask ? attn_bias + centered antisymmetric dir bias : -inf
// ---------------------------------------------------------------------------
__global__ __launch_bounds__(128) void bias_prep_kernel(
    const float* __restrict__ dir_vec, const float* __restrict__ attn_bias,
    const float* __restrict__ disp, const unsigned char* __restrict__ maskb,
    const int* __restrict__ flag, float* __restrict__ comb)
{
    const int i = blockIdx.x, h = blockIdx.y, j = threadIdx.x;
    __shared__ float red[128];

    float dv = dir_vec[h * C_ + j];
    red[j] = dv * dv;
    __syncthreads();
    for (int s = 64; s > 0; s >>= 1) {
        if (j < s) red[j] += red[j + s];
        __syncthreads();
    }
    const float nrm = fmaxf(sqrtf(red[0]), 1e-12f);
    __syncthreads();

    const float dvn_j = dir_vec[h * C_ + j] / nrm;
    const float dvn_i = dir_vec[h * C_ + i] / nrm;
    const float third = 1.0f / 3.0f;
    const float dm_ij = (disp[(i * C_ + j) * 3 + 0] + disp[(i * C_ + j) * 3 + 1] +
                         disp[(i * C_ + j) * 3 + 2]) * third;
    const float dm_ji = (disp[(j * C_ + i) * 3 + 0] + disp[(j * C_ + i) * 3 + 1] +
                         disp[(j * C_ + i) * 3 + 2]) * third;
    const float db = 0.5f * (dm_ij * dvn_j - dm_ji * dvn_i);

    red[j] = db;
    __syncthreads();
    for (int s = 64; s > 0; s >>= 1) {
        if (j < s) red[j] += red[j + s];
        __syncthreads();
    }
    const float rowmean = red[0] * (1.0f / 128.0f);

    const bool mk = (*flag) ? (maskb[i * C_ + j] != 0)
                            : (((const int*)maskb)[i * C_ + j] != 0);
    comb[((size_t)h * C_ + i) * C_ + j] =
        mk ? (attn_bias[i * C_ + j] + db - rowmean) : -INFINITY;
}

// ---------------------------------------------------------------------------
// Split the 4 weight matrices [E][E] fp32 -> hi/lo bf16 (layout preserved).
// ---------------------------------------------------------------------------
__global__ __launch_bounds__(256) void wsplit_kernel(
    const float* __restrict__ w0, const float* __restrict__ w1,
    const float* __restrict__ w2, const float* __restrict__ w3,
    ushort* __restrict__ wh, ushort* __restrict__ wl)
{
    const int s = blockIdx.y;
    const float* __restrict__ w = (s == 0) ? w0 : (s == 1) ? w1 : (s == 2) ? w2 : w3;
    const size_t base = (size_t)s * E_ * E_;
    const size_t i0 = ((size_t)blockIdx.x * 256 + threadIdx.x) * 8;
    const float4 f0 = *(const float4*)&w[i0];
    const float4 f1 = *(const float4*)&w[i0 + 4];
    const float ff[8] = {f0.x, f0.y, f0.z, f0.w, f1.x, f1.y, f1.z, f1.w};
    union { ushort u[8]; uint4 v; } hu, lu;
#pragma unroll
    for (int j = 0; j < 8; ++j) {
        const ushort hb = f2bf(ff[j]);
        hu.u[j] = hb;
        lu.u[j] = f2bf(ff[j] - bf2f(hb));
    }
    *(uint4*)&wh[base + i0] = hu.v;
    *(uint4*)&wl[base + i0] = lu.v;
}

// ---------------------------------------------------------------------------
// x [B][E][C] fp32 -> xT hi/lo bf16 [B][C][E]  (transpose + split)
// ---------------------------------------------------------------------------
__global__ __launch_bounds__(256) void xsplit_kernel(
    const float* __restrict__ x, ushort* __restrict__ xh, ushort* __restrict__ xl)
{
    const int b = blockIdx.y, e0 = blockIdx.x * 64;
    __shared__ float ts[64][132];
    const int tid = threadIdx.x;
    const float* __restrict__ xb = x + ((size_t)b * E_ + e0) * C_;
#pragma unroll
    for (int r = 0; r < 8; ++r) {
        const int idx = tid + r * 256;        // 0..2047 float4s
        const int e = idx >> 5, c4 = idx & 31;
        *(float4*)&ts[e][c4 * 4] = *(const float4*)&xb[(size_t)e * C_ + c4 * 4];
    }
    __syncthreads();
    const int lc = tid >> 3;           // 0..31
    const int l8 = (tid & 7) * 8;      // e chunk within 64
#pragma unroll
    for (int p = 0; p < 4; ++p) {
        const int c = p * 32 + lc;
        union { ushort u[8]; uint4 v; } hu, lu;
#pragma unroll
        for (int j = 0; j < 8; ++j) {
            const float f = ts[l8 + j][c];
            const ushort hb = f2bf(f);
            hu.u[j] = hb;
            lu.u[j] = f2bf(f - bf2f(hb));
        }
        const size_t rb = ((size_t)b * C_ + c) * E_ + e0 + l8;
        *(uint4*)&xh[rb] = hu.v;
        *(uint4*)&xl[rb] = lu.v;
    }
}

// ---------------------------------------------------------------------------
// Split-bf16 MFMA GEMM: out[o][c] = selu(sum_e W[o][e]*Bmat[c][e]) per (b,z).
// 128x128 tile, BK=64, 4 waves x (4x4 x mfma_f32_16x16x32_bf16), 3-term split.
// W row-major [o][e]; B transposed [b][c][e]; both staged via global_load_lds.
// ---------------------------------------------------------------------------
__global__ __launch_bounds__(256, 2) void gemm_split_kernel(
    const ushort* __restrict__ Wh0, const ushort* __restrict__ Wh1,
    const ushort* __restrict__ Wh2, const ushort* __restrict__ Wl0,
    const ushort* __restrict__ Wl1, const ushort* __restrict__ Wl2,
    const ushort* __restrict__ Bh, const ushort* __restrict__ Bl,
    float* __restrict__ out, size_t zstride)
{
    const int p = blockIdx.z;
    const ushort* __restrict__ wh = (p == 0) ? Wh0 : (p == 1) ? Wh1 : Wh2;
    const ushort* __restrict__ wl = (p == 0) ? Wl0 : (p == 1) ? Wl1 : Wl2;
    const int b = blockIdx.y;
    const int o0 = blockIdx.x * 128;

    __shared__ ushort As_hi[128 * 64];   // [o][k] 16 KB
    __shared__ ushort As_lo[128 * 64];
    __shared__ ushort Bs_hi[128 * 64];   // [c][k]
    __shared__ ushort Bs_lo[128 * 64];

    const int tid = threadIdx.x;
    const int wid = tid >> 6, lane = tid & 63;
    const int wr64 = (wid >> 1) * 64, wc64 = (wid & 1) * 64;
    const int w4 = wid * 4;
    const int srow = lane >> 3;
    const size_t gco = (size_t)(lane & 7) * 16;   // byte col offset in 128B row

    const char* __restrict__ bhp = (const char*)(Bh + (size_t)b * C_ * E_);
    const char* __restrict__ blp = (const char*)(Bl + (size_t)b * C_ * E_);
    const char* __restrict__ whp = (const char*)wh;
    const char* __restrict__ wlp = (const char*)wl;

    f32x4 acc[4][4];
#pragma unroll
    for (int m = 0; m < 4; ++m)
#pragma unroll
        for (int n = 0; n < 4; ++n) acc[m][n] = (f32x4)0.0f;

    for (int k0 = 0; k0 < E_; k0 += 64) {
#pragma unroll
        for (int t = 0; t < 4; ++t) {
            const int inst = w4 + t;                  // 0..15, 8 rows each
            const int r = inst * 8 + srow;
            const size_t arow = ((size_t)(o0 + r) * E_ + k0) * 2 + gco;
            const size_t brow = ((size_t)r * E_ + k0) * 2 + gco;
            gll16(whp + arow, &As_hi[inst * 512]);
            gll16(wlp + arow, &As_lo[inst * 512]);
            gll16(bhp + brow, &Bs_hi[inst * 512]);
            gll16(blp + brow, &Bs_lo[inst * 512]);
        }
        __syncthreads();
#pragma unroll
        for (int kk = 0; kk < 2; ++kk) {
            const int ko = kk * 32 + (lane >> 4) * 8;
            bf16x8 ah[4], al[4], bh[4], bl[4];
#pragma unroll
            for (int m = 0; m < 4; ++m) {
                const int r = wr64 + m * 16 + (lane & 15);
                ah[m] = *(const bf16x8*)&As_hi[r * 64 + ko];
                al[m] = *(const bf16x8*)&As_lo[r * 64 + ko];
            }
#pragma unroll
            for (int n = 0; n < 4; ++n) {
                const int c = wc64 + n * 16 + (lane & 15);
                bh[n] = *(const bf16x8*)&Bs_hi[c * 64 + ko];
                bl[n] = *(const bf16x8*)&Bs_lo[c * 64 + ko];
            }
#pragma unroll
            for (int m = 0; m < 4; ++m)
#pragma unroll
                for (int n = 0; n < 4; ++n)
                    acc[m][n] = __builtin_amdgcn_mfma_f32_16x16x32_bf16(
                        ah[m], bh[n], acc[m][n], 0, 0, 0);
#pragma unroll
            for (int m = 0; m < 4; ++m)
#pragma unroll
                for (int n = 0; n < 4; ++n)
                    acc[m][n] = __builtin_amdgcn_mfma_f32_16x16x32_bf16(
                        ah[m], bl[n], acc[m][n], 0, 0, 0);
#pragma unroll
            for (int m = 0; m < 4; ++m)
#pragma unroll
                for (int n = 0; n < 4; ++n)
                    acc[m][n] = __builtin_amdgcn_mfma_f32_16x16x32_bf16(
                        al[m], bh[n], acc[m][n], 0, 0, 0);
        }
        __syncthreads();
    }

    float* __restrict__ outb = out + (size_t)p * zstride + (size_t)b * E_ * C_;
    const int lr = (lane >> 4) * 4, lc = lane & 15;   // C/D: col=lane&15
#pragma unroll
    for (int m = 0; m < 4; ++m)
#pragma unroll
        for (int n = 0; n < 4; ++n) {
            float* po = outb + (size_t)(o0 + wr64 + m * 16 + lr) * C_ +
                        wc64 + n * 16 + lc;
            const f32x4 a = acc[m][n];
#pragma unroll
            for (int j = 0; j < 4; ++j) po[(size_t)j * C_] = selu_f(a[j]);
        }
}

// ---------------------------------------------------------------------------
// Attention per (b,h): scores = q^T k * 0.125 + comb (mask folded), softmax,
// attn = p @ v^T. Epilogue writes TRANSPOSED split-bf16 attnT[b][c][e].
// ---------------------------------------------------------------------------
__global__ __launch_bounds__(256) void attn_kernel(
    const float* __restrict__ qkv, const float* __restrict__ comb,
    ushort* __restrict__ aTh, ushort* __restrict__ aTl)
{
    const int b = blockIdx.x, h = blockIdx.y;
    __shared__ float qs[D_ * C_];      // reused for v in phase 2
    __shared__ float ks[D_ * C_];
    __shared__ float ps[C_][129];

    const int tid = threadIdx.x;
    const size_t base = ((size_t)b * E_ + h * D_) * C_;
    const float* __restrict__ qg = qkv + base;
    const float* __restrict__ kg = qkv + BEC_ + base;
    const float* __restrict__ vg = qkv + 2 * BEC_ + base;

#pragma unroll
    for (int r = 0; r < 8; ++r) {
        const int idx = (tid + r * 256) * 4;
        *(float4*)&qs[idx] = *(const float4*)&qg[idx];
        *(float4*)&ks[idx] = *(const float4*)&kg[idx];
    }
    __syncthreads();

    const int ti = tid >> 4, tj = tid & 15;
    const int i0 = ti * 8, j0 = tj * 8;

    float acc[8][8];
#pragma unroll
    for (int ii = 0; ii < 8; ++ii)
#pragma unroll
        for (int jj = 0; jj < 8; ++jj) acc[ii][jj] = 0.0f;

#pragma unroll 4
    for (int d = 0; d < D_; ++d) {
        float a0[8], b0[8];
        *(float4*)&a0[0] = *(float4*)&qs[d * C_ + i0];
        *(float4*)&a0[4] = *(float4*)&qs[d * C_ + i0 + 4];
        *(float4*)&b0[0] = *(float4*)&ks[d * C_ + j0];
        *(float4*)&b0[4] = *(float4*)&ks[d * C_ + j0 + 4];
#pragma unroll
        for (int ii = 0; ii < 8; ++ii)
#pragma unroll
            for (int jj = 0; jj < 8; ++jj) acc[ii][jj] += a0[ii] * b0[jj];
    }

    const float* __restrict__ cb = comb + (size_t)h * C_ * C_;
#pragma unroll
    for (int ii = 0; ii < 8; ++ii) {
        const int i = i0 + ii;
        float s[8];
        float m = -INFINITY;
#pragma unroll
        for (int jj = 0; jj < 8; ++jj) {
            s[jj] = acc[ii][jj] * 0.125f + cb[i * C_ + j0 + jj];
            m = fmaxf(m, s[jj]);
        }
#pragma unroll
        for (int off = 1; off < 16; off <<= 1) m = fmaxf(m, __shfl_xor(m, off));
        float sum = 0.0f;
#pragma unroll
        for (int jj = 0; jj < 8; ++jj) {
            s[jj] = __expf(s[jj] - m);
            sum += s[jj];
        }
#pragma unroll
        for (int off = 1; off < 16; off <<= 1) sum += __shfl_xor(sum, off);
        const float inv = 1.0f / sum;
#pragma unroll
        for (int jj = 0; jj < 8; ++jj) ps[i][j0 + jj] = s[jj] * inv;
    }
    __syncthreads();

#pragma unroll
    for (int r = 0; r < 8; ++r) {
        const int idx = (tid + r * 256) * 4;
        *(float4*)&qs[idx] = *(const float4*)&vg[idx];
    }
    __syncthreads();

    const int td = tid >> 5, tc = tid & 31;
    const int dd0 = td * 8, ic0 = tc * 4;
    float acc2[8][4];
#pragma unroll
    for (int dd = 0; dd < 8; ++dd)
#pragma unroll
        for (int ii = 0; ii < 4; ++ii) acc2[dd][ii] = 0.0f;

#pragma unroll 2
    for (int j = 0; j < C_; ++j) {
        float vv[8], pv[4];
#pragma unroll
        for (int dd = 0; dd < 8; ++dd) vv[dd] = qs[(dd0 + dd) * C_ + j];
#pragma unroll
        for (int ii = 0; ii < 4; ++ii) pv[ii] = ps[ic0 + ii][j];
#pragma unroll
        for (int dd = 0; dd < 8; ++dd)
#pragma unroll
            for (int ii = 0; ii < 4; ++ii) acc2[dd][ii] += vv[dd] * pv[ii];
    }

    // transposed split-bf16 store: attnT[b][c][h*64 + d]
#pragma unroll
    for (int ii = 0; ii < 4; ++ii) {
        const int c = ic0 + ii;
        union { ushort u[8]; uint4 v; } hu, lu;
#pragma unroll
        for (int dd = 0; dd < 8; ++dd) {
            const float f = acc2[dd][ii];
            const ushort hb = f2bf(f);
            hu.u[dd] = hb;
            lu.u[dd] = f2bf(f - bf2f(hb));
        }
        const size_t rb = ((size_t)b * C_ + c) * E_ + h * D_ + dd0;
        *(uint4*)&aTh[rb] = hu.v;
        *(uint4*)&aTl[rb] = lu.v;
    }
}

// ---------------------------------------------------------------------------
extern "C" void kernel_launch(void* const* d_in, const int* in_sizes, int n_in,
                              void* d_out, int out_size, void* d_ws, size_t ws_size,
                              hipStream_t stream) {
    const float* x        = (const float*)d_in[0];
    const float* wq       = (const float*)d_in[1];
    const float* wk       = (const float*)d_in[2];
    const float* wv       = (const float*)d_in[3];
    const float* wo       = (const float*)d_in[4];
    const float* dir_vec  = (const float*)d_in[5];
    const float* attn_b   = (const float*)d_in[6];
    const float* disp     = (const float*)d_in[7];
    const unsigned char* knn = (const unsigned char*)d_in[8];
    float* out = (float*)d_out;

    // workspace layout (~139 MB peak)
    char* ws = (char*)d_ws;
    float* qkv = (float*)ws;                           // 3*BEC f32 (100.7 MB)
    size_t off = 3 * BEC_ * sizeof(float);
    ushort* xTh = (ushort*)(ws + off); off += BEC_ * 2; // 16.8 MB (reused as attnT_hi)
    ushort* xTl = (ushort*)(ws + off); off += BEC_ * 2; // 16.8 MB (reused as attnT_lo)
    ushort* wh  = (ushort*)(ws + off); off += (size_t)4 * E_ * E_ * 2;  // 2 MB
    ushort* wl  = (ushort*)(ws + off); off += (size_t)4 * E_ * E_ * 2;  // 2 MB
    float* comb = (float*)(ws + off);  off += (size_t)H_ * C_ * C_ * sizeof(float);
    int* flag   = (int*)(ws + off);

    detect_mask_kernel<<<1, 256, 0, stream>>>(knn, flag);
    bias_prep_kernel<<<dim3(C_, H_), 128, 0, stream>>>(dir_vec, attn_b, disp, knn,
                                                       flag, comb);
    wsplit_kernel<<<dim3(128, 4), 256, 0, stream>>>(wq, wk, wv, wo, wh, wl);
    xsplit_kernel<<<dim3(8, B_), 256, 0, stream>>>(x, xTh, xTl);

    const size_t WSZ = (size_t)E_ * E_;
    // q,k,v projections with fused SELU -> fp32 qkv buffer
    gemm_split_kernel<<<dim3(4, B_, 3), 256, 0, stream>>>(
        wh, wh + WSZ, wh + 2 * WSZ, wl, wl + WSZ, wl + 2 * WSZ,
        xTh, xTl, qkv, BEC_);
    // attention -> transposed split-bf16 attnT over the (now dead) xT buffers
    attn_kernel<<<dim3(B_, H_), 256, 0, stream>>>(qkv, comb, xTh, xTl);
    // output projection with fused SELU -> d_out
    gemm_split_kernel<<<dim3(4, B_, 1), 256, 0, stream>>>(
        wh + 3 * WSZ, wh + 3 * WSZ, wh + 3 * WSZ,
        wl + 3 * WSZ, wl + 3 * WSZ, wl + 3 * WSZ,
        xTh, xTl, out, 0);
}

// Round 4
// 215.007 us; speedup vs baseline: 2.7673x; 1.3191x over previous
//
#include <hip/hip_runtime.h>
#include <math.h>

#define B_ 128
#define E_ 512
#define C_ 128
#define H_ 8
#define D_ 64
#define BEC_ ((size_t)B_ * E_ * C_)

typedef __attribute__((ext_vector_type(8))) __bf16 bf16x8;
typedef __attribute__((ext_vector_type(4))) float f32x4;

__device__ __forceinline__ ushort f2bf(float f) {
    unsigned u = __float_as_uint(f);
    unsigned r = u + 0x7fffu + ((u >> 16) & 1u);
    return (ushort)(r >> 16);
}
__device__ __forceinline__ float bf2f(ushort h) {
    return __uint_as_float(((unsigned)h) << 16);
}
__device__ __forceinline__ void split_bf(float f, ushort& hi, ushort& lo) {
    hi = f2bf(f);
    lo = f2bf(f - bf2f(hi));
}
__device__ __forceinline__ float selu_f(float x) {
    const float alpha = 1.6732632423543772f;
    const float scale = 1.0507009873554805f;
    return x > 0.0f ? scale * x : scale * alpha * expm1f(x);
}
// async global->LDS, 16B/lane; LDS dest wave-uniform base + lane*16
__device__ __forceinline__ void gll16(const void* g, void* l) {
    __builtin_amdgcn_global_load_lds(
        (const __attribute__((address_space(1))) void*)g,
        (__attribute__((address_space(3))) void*)l, 16, 0, 0);
}

// ---------------------------------------------------------------------------
// knn_mask dtype sniff (bool bytes -> 2688 nonzero in 16KB, int32 -> 672)
// ---------------------------------------------------------------------------
__global__ void detect_mask_kernel(const unsigned char* __restrict__ m,
                                   int* __restrict__ flag) {
    __shared__ int cnt;
    if (threadIdx.x == 0) cnt = 0;
    __syncthreads();
    int local = 0;
    for (int i = threadIdx.x; i < C_ * C_; i += blockDim.x) local += (m[i] != 0);
    atomicAdd(&cnt, local);
    __syncthreads();
    if (threadIdx.x == 0) *flag = (cnt > 1600) ? 1 : 0;
}

// ---------------------------------------------------------------------------
// combT[h][j][i] = mask(i,j) ? attn_bias[i][j] + centered dir bias(i,j) : -inf
// TRANSPOSED store so the attention kernel loads 4 consecutive i as float4.
// ---------------------------------------------------------------------------
__global__ __launch_bounds__(128) void bias_prep_kernel(
    const float* __restrict__ dir_vec, const float* __restrict__ attn_bias,
    const float* __restrict__ disp, const unsigned char* __restrict__ maskb,
    const int* __restrict__ flag, float* __restrict__ combT)
{
    const int i = blockIdx.x, h = blockIdx.y, j = threadIdx.x;
    __shared__ float red[128];

    float dv = dir_vec[h * C_ + j];
    red[j] = dv * dv;
    __syncthreads();
    for (int s = 64; s > 0; s >>= 1) {
        if (j < s) red[j] += red[j + s];
        __syncthreads();
    }
    const float nrm = fmaxf(sqrtf(red[0]), 1e-12f);
    __syncthreads();

    const float dvn_j = dir_vec[h * C_ + j] / nrm;
    const float dvn_i = dir_vec[h * C_ + i] / nrm;
    const float third = 1.0f / 3.0f;
    const float dm_ij = (disp[(i * C_ + j) * 3 + 0] + disp[(i * C_ + j) * 3 + 1] +
                         disp[(i * C_ + j) * 3 + 2]) * third;
    const float dm_ji = (disp[(j * C_ + i) * 3 + 0] + disp[(j * C_ + i) * 3 + 1] +
                         disp[(j * C_ + i) * 3 + 2]) * third;
    const float db = 0.5f * (dm_ij * dvn_j - dm_ji * dvn_i);

    red[j] = db;
    __syncthreads();
    for (int s = 64; s > 0; s >>= 1) {
        if (j < s) red[j] += red[j + s];
        __syncthreads();
    }
    const float rowmean = red[0] * (1.0f / 128.0f);

    const bool mk = (*flag) ? (maskb[i * C_ + j] != 0)
                            : (((const int*)maskb)[i * C_ + j] != 0);
    combT[((size_t)h * C_ + j) * C_ + i] =
        mk ? (attn_bias[i * C_ + j] + db - rowmean) : -INFINITY;
}

// ---------------------------------------------------------------------------
// Split the 4 weight matrices [E][E] fp32 -> hi/lo bf16 (layout preserved).
// ---------------------------------------------------------------------------
__global__ __launch_bounds__(256) void wsplit_kernel(
    const float* __restrict__ w0, const float* __restrict__ w1,
    const float* __restrict__ w2, const float* __restrict__ w3,
    ushort* __restrict__ wh, ushort* __restrict__ wl)
{
    const int s = blockIdx.y;
    const float* __restrict__ w = (s == 0) ? w0 : (s == 1) ? w1 : (s == 2) ? w2 : w3;
    const size_t base = (size_t)s * E_ * E_;
    const size_t i0 = ((size_t)blockIdx.x * 256 + threadIdx.x) * 8;
    const float4 f0 = *(const float4*)&w[i0];
    const float4 f1 = *(const float4*)&w[i0 + 4];
    const float ff[8] = {f0.x, f0.y, f0.z, f0.w, f1.x, f1.y, f1.z, f1.w};
    union { ushort u[8]; uint4 v; } hu, lu;
#pragma unroll
    for (int j = 0; j < 8; ++j) split_bf(ff[j], hu.u[j], lu.u[j]);
    *(uint4*)&wh[base + i0] = hu.v;
    *(uint4*)&wl[base + i0] = lu.v;
}

// ---------------------------------------------------------------------------
// x [B][E][C] fp32 -> xT hi/lo bf16 [B][C][E]  (transpose + split)
// ---------------------------------------------------------------------------
__global__ __launch_bounds__(256) void xsplit_kernel(
    const float* __restrict__ x, ushort* __restrict__ xh, ushort* __restrict__ xl)
{
    const int b = blockIdx.y, e0 = blockIdx.x * 64;
    __shared__ float ts[64][132];
    const int tid = threadIdx.x;
    const float* __restrict__ xb = x + ((size_t)b * E_ + e0) * C_;
#pragma unroll
    for (int r = 0; r < 8; ++r) {
        const int idx = tid + r * 256;
        const int e = idx >> 5, c4 = idx & 31;
        *(float4*)&ts[e][c4 * 4] = *(const float4*)&xb[(size_t)e * C_ + c4 * 4];
    }
    __syncthreads();
    const int lc = tid >> 3;
    const int l8 = (tid & 7) * 8;
#pragma unroll
    for (int p = 0; p < 4; ++p) {
        const int c = p * 32 + lc;
        union { ushort u[8]; uint4 v; } hu, lu;
#pragma unroll
        for (int j = 0; j < 8; ++j) split_bf(ts[l8 + j][c], hu.u[j], lu.u[j]);
        const size_t rb = ((size_t)b * C_ + c) * E_ + e0 + l8;
        *(uint4*)&xh[rb] = hu.v;
        *(uint4*)&xl[rb] = lu.v;
    }
}

// ---------------------------------------------------------------------------
// Split-bf16 MFMA GEMM, 128x128 tile, BK=64, 4 waves x 4x4 frags, 3 terms.
// MODE 0 (qkv): z=0 q -> TRANSPOSED split store qT[b][c][E]
//               z=1 k -> TRANSPOSED split store kT[b][c][E]
//               z=2 v -> natural hi-only store v[b][E][C]
// MODE 1 (out): natural fp32 selu store to d_out.
// Transpose is free: swap which LDS tile feeds A-frags vs B-frags.
// ---------------------------------------------------------------------------
template<int MODE>
__global__ __launch_bounds__(256, 2) void gemm_kernel(
    const ushort* __restrict__ Wh0, const ushort* __restrict__ Wh1,
    const ushort* __restrict__ Wh2, const ushort* __restrict__ Wl0,
    const ushort* __restrict__ Wl1, const ushort* __restrict__ Wl2,
    const ushort* __restrict__ Bh, const ushort* __restrict__ Bl,
    ushort* __restrict__ qh, ushort* __restrict__ ql,
    ushort* __restrict__ kh, ushort* __restrict__ kl,
    ushort* __restrict__ vhp, float* __restrict__ fout)
{
    const int z = (MODE == 0) ? blockIdx.z : 0;
    const ushort* __restrict__ wh = (z == 0) ? Wh0 : (z == 1) ? Wh1 : Wh2;
    const ushort* __restrict__ wl = (z == 0) ? Wl0 : (z == 1) ? Wl1 : Wl2;
    const bool trans = (MODE == 0) && (z < 2);
    const int b = blockIdx.y;
    const int o0 = blockIdx.x * 128;

    __shared__ ushort sm[4 * 8192];   // Whi | Wlo | Xhi | Xlo, each [128][64]

    const int tid = threadIdx.x;
    const int wid = tid >> 6, lane = tid & 63;
    const int wr64 = (wid >> 1) * 64, wc64 = (wid & 1) * 64;
    const int w4 = wid * 4;
    const int srow = lane >> 3;
    const size_t gco = (size_t)(lane & 7) * 16;

    const char* __restrict__ bhp = (const char*)(Bh + (size_t)b * C_ * E_);
    const char* __restrict__ blp = (const char*)(Bl + (size_t)b * C_ * E_);
    const char* __restrict__ whp = (const char*)wh;
    const char* __restrict__ wlp = (const char*)wl;

    const int aoff = trans ? 16384 : 0;     // A-frags from X tile if trans
    const int boff = trans ? 0 : 16384;

    f32x4 acc[4][4];
#pragma unroll
    for (int m = 0; m < 4; ++m)
#pragma unroll
        for (int n = 0; n < 4; ++n) acc[m][n] = (f32x4)0.0f;

    for (int k0 = 0; k0 < E_; k0 += 64) {
#pragma unroll
        for (int t = 0; t < 4; ++t) {
            const int inst = w4 + t;
            const int r = inst * 8 + srow;
            const size_t arow = ((size_t)(o0 + r) * E_ + k0) * 2 + gco;
            const size_t brow = ((size_t)r * E_ + k0) * 2 + gco;
            gll16(whp + arow, &sm[inst * 512]);
            gll16(wlp + arow, &sm[8192 + inst * 512]);
            gll16(bhp + brow, &sm[16384 + inst * 512]);
            gll16(blp + brow, &sm[24576 + inst * 512]);
        }
        __syncthreads();
#pragma unroll
        for (int kk = 0; kk < 2; ++kk) {
            const int ko = kk * 32 + (lane >> 4) * 8;
            bf16x8 ah[4], al[4], bh4[4], bl4[4];
#pragma unroll
            for (int m = 0; m < 4; ++m) {
                const int r = wr64 + m * 16 + (lane & 15);
                ah[m] = *(const bf16x8*)&sm[aoff + r * 64 + ko];
                al[m] = *(const bf16x8*)&sm[aoff + 8192 + r * 64 + ko];
            }
#pragma unroll
            for (int n = 0; n < 4; ++n) {
                const int c = wc64 + n * 16 + (lane & 15);
                bh4[n] = *(const bf16x8*)&sm[boff + c * 64 + ko];
                bl4[n] = *(const bf16x8*)&sm[boff + 8192 + c * 64 + ko];
            }
#pragma unroll
            for (int m = 0; m < 4; ++m)
#pragma unroll
                for (int n = 0; n < 4; ++n)
                    acc[m][n] = __builtin_amdgcn_mfma_f32_16x16x32_bf16(
                        ah[m], bh4[n], acc[m][n], 0, 0, 0);
#pragma unroll
            for (int m = 0; m < 4; ++m)
#pragma unroll
                for (int n = 0; n < 4; ++n)
                    acc[m][n] = __builtin_amdgcn_mfma_f32_16x16x32_bf16(
                        ah[m], bl4[n], acc[m][n], 0, 0, 0);
#pragma unroll
            for (int m = 0; m < 4; ++m)
#pragma unroll
                for (int n = 0; n < 4; ++n)
                    acc[m][n] = __builtin_amdgcn_mfma_f32_16x16x32_bf16(
                        al[m], bh4[n], acc[m][n], 0, 0, 0);
        }
        __syncthreads();
    }

    const int lr = (lane >> 4) * 4, lc = lane & 15;   // C/D: col=lane&15
    if (MODE == 1) {
        float* __restrict__ outb = fout + (size_t)b * E_ * C_;
#pragma unroll
        for (int m = 0; m < 4; ++m)
#pragma unroll
            for (int n = 0; n < 4; ++n) {
                float* po = outb + (size_t)(o0 + wr64 + m * 16 + lr) * C_ +
                            wc64 + n * 16 + lc;
                const f32x4 a = acc[m][n];
#pragma unroll
                for (int j = 0; j < 4; ++j) po[(size_t)j * C_] = selu_f(a[j]);
            }
    } else if (z == 2) {
        // v: natural [b][E][C], hi only
#pragma unroll
        for (int m = 0; m < 4; ++m)
#pragma unroll
            for (int n = 0; n < 4; ++n) {
                const f32x4 a = acc[m][n];
#pragma unroll
                for (int j = 0; j < 4; ++j) {
                    const size_t idx = ((size_t)b * E_ + o0 + wr64 + m * 16 + lr + j) * C_ +
                                       wc64 + n * 16 + lc;
                    vhp[idx] = f2bf(selu_f(a[j]));
                }
            }
    } else {
        // q/k: transposed [b][c][E], split hi/lo. rows=c, cols=o.
        ushort* __restrict__ th = z ? kh : qh;
        ushort* __restrict__ tl = z ? kl : ql;
#pragma unroll
        for (int m = 0; m < 4; ++m)
#pragma unroll
            for (int n = 0; n < 4; ++n) {
                const f32x4 a = acc[m][n];
#pragma unroll
                for (int j = 0; j < 4; ++j) {
                    const int c = wr64 + m * 16 + lr + j;
                    const int o = o0 + wc64 + n * 16 + lc;
                    const size_t idx = ((size_t)b * C_ + c) * E_ + o;
                    ushort hi, lo;
                    split_bf(selu_f(a[j]), hi, lo);
                    th[idx] = hi;
                    tl[idx] = lo;
                }
            }
    }
}

// ---------------------------------------------------------------------------
// MFMA attention, one block (4 waves) per (b,h). 80 KB LDS -> 2 blocks/CU.
// QK^T: 3-term split. Softmax in registers (wave owns 32 full rows).
// P split hi/lo -> LDS (overlays q/k staging). PV: (P_hi+P_lo) x v_hi.
// All LDS tiles XOR-swizzled: byte ^= (row&7)<<4, source pre-swizzled.
// ---------------------------------------------------------------------------
__global__ __launch_bounds__(256, 2) void attn_mfma_kernel(
    const ushort* __restrict__ qTh, const ushort* __restrict__ qTl,
    const ushort* __restrict__ kTh, const ushort* __restrict__ kTl,
    const ushort* __restrict__ vh,  const float* __restrict__ combT,
    ushort* __restrict__ aTh, ushort* __restrict__ aTl)
{
    const int b = blockIdx.x, h = blockIdx.y;
    __shared__ ushort lds[40960];          // 80 KB
    ushort* sQh = lds;                     // [128][64] 16 KB
    ushort* sQl = lds + 8192;
    ushort* sKh = lds + 16384;
    ushort* sKl = lds + 24576;
    ushort* sV  = lds + 32768;             // [64][128] 16 KB
    ushort* sPh = lds;                     // overlays q/k: [128][128] 32 KB
    ushort* sPl = lds + 16384;

    const int tid = threadIdx.x, wid = tid >> 6, lane = tid & 63;

    // ---- stage q,k ([128][64], swizzled src) + v ([64][128], swizzled src)
    {
        const size_t gq = (size_t)b * C_ * E_ + h * D_;
        const int rsub = lane >> 3, chunk = lane & 7;
#pragma unroll
        for (int t = 0; t < 4; ++t) {
            const int inst = wid * 4 + t;
            const int row = inst * 8 + rsub;
            const size_t goff = (gq + (size_t)row * E_) * 2 +
                                (size_t)(chunk ^ (row & 7)) * 16;
            gll16((const char*)qTh + goff, &sQh[inst * 512]);
            gll16((const char*)qTl + goff, &sQl[inst * 512]);
            gll16((const char*)kTh + goff, &sKh[inst * 512]);
            gll16((const char*)kTl + goff, &sKl[inst * 512]);
        }
        const size_t gv = ((size_t)b * E_ + h * D_) * C_;
        const int vr = lane >> 4, vchunk = lane & 15;
#pragma unroll
        for (int t = 0; t < 4; ++t) {
            const int inst = wid * 4 + t;
            const int row = inst * 4 + vr;
            const size_t goff = (gv + (size_t)row * C_) * 2 +
                                (size_t)(vchunk ^ (row & 7)) * 16;
            gll16((const char*)vh + goff, &sV[inst * 512]);
        }
    }
    __syncthreads();

    const int i0 = wid * 32;       // this wave's 32 score rows
    const int l15 = lane & 15;

    // ---- QK^T: scores 32x128 per wave = 2 m-frags x 8 n-frags, K=64
    f32x4 acc[2][8];
#pragma unroll
    for (int m = 0; m < 2; ++m)
#pragma unroll
        for (int n = 0; n < 8; ++n) acc[m][n] = (f32x4)0.0f;

#pragma unroll
    for (int kk = 0; kk < 2; ++kk) {
        const int kbyte = kk * 64 + (lane >> 4) * 16;
        bf16x8 qhf[2], qlf[2];
#pragma unroll
        for (int m = 0; m < 2; ++m) {
            const int r = i0 + m * 16 + l15;
            const int byt = r * 128 + (kbyte ^ ((r & 7) << 4));
            qhf[m] = *(const bf16x8*)((const char*)sQh + byt);
            qlf[m] = *(const bf16x8*)((const char*)sQl + byt);
        }
#pragma unroll
        for (int n = 0; n < 8; ++n) {
            const int r = n * 16 + l15;
            const int byt = r * 128 + (kbyte ^ ((r & 7) << 4));
            const bf16x8 khf = *(const bf16x8*)((const char*)sKh + byt);
            const bf16x8 klf = *(const bf16x8*)((const char*)sKl + byt);
#pragma unroll
            for (int m = 0; m < 2; ++m) {
                acc[m][n] = __builtin_amdgcn_mfma_f32_16x16x32_bf16(
                    qhf[m], khf, acc[m][n], 0, 0, 0);
                acc[m][n] = __builtin_amdgcn_mfma_f32_16x16x32_bf16(
                    qhf[m], klf, acc[m][n], 0, 0, 0);
                acc[m][n] = __builtin_amdgcn_mfma_f32_16x16x32_bf16(
                    qlf[m], khf, acc[m][n], 0, 0, 0);
            }
        }
    }

    // ---- bias (combT float4) + masked softmax, fully in registers
#pragma unroll
    for (int m = 0; m < 2; ++m)
#pragma unroll
        for (int n = 0; n < 8; ++n) {
            const int jcol = n * 16 + l15;
            const float4 cb = *(const float4*)&combT[
                ((size_t)h * C_ + jcol) * C_ + i0 + m * 16 + (lane >> 4) * 4];
            acc[m][n][0] = fmaf(acc[m][n][0], 0.125f, cb.x);
            acc[m][n][1] = fmaf(acc[m][n][1], 0.125f, cb.y);
            acc[m][n][2] = fmaf(acc[m][n][2], 0.125f, cb.z);
            acc[m][n][3] = fmaf(acc[m][n][3], 0.125f, cb.w);
        }

#pragma unroll
    for (int m = 0; m < 2; ++m)
#pragma unroll
        for (int jj = 0; jj < 4; ++jj) {
            float mx = -INFINITY;
#pragma unroll
            for (int n = 0; n < 8; ++n) mx = fmaxf(mx, acc[m][n][jj]);
#pragma unroll
            for (int off = 1; off < 16; off <<= 1)
                mx = fmaxf(mx, __shfl_xor(mx, off));
            float sum = 0.0f;
#pragma unroll
            for (int n = 0; n < 8; ++n) {
                const float e = __expf(acc[m][n][jj] - mx);
                acc[m][n][jj] = e;
                sum += e;
            }
#pragma unroll
            for (int off = 1; off < 16; off <<= 1) sum += __shfl_xor(sum, off);
            const float inv = 1.0f / sum;
#pragma unroll
            for (int n = 0; n < 8; ++n) acc[m][n][jj] *= inv;
        }

    // ---- P -> LDS (split, swizzled). Must not race q/k reads: barrier first.
    __syncthreads();
#pragma unroll
    for (int m = 0; m < 2; ++m)
#pragma unroll
        for (int n = 0; n < 8; ++n)
#pragma unroll
            for (int jj = 0; jj < 4; ++jj) {
                const int i = i0 + m * 16 + (lane >> 4) * 4 + jj;
                const int col = n * 16 + l15;
                const int byt = i * 256 + ((col * 2) ^ ((i & 7) << 4));
                ushort hi, lo;
                split_bf(acc[m][n][jj], hi, lo);
                *(ushort*)((char*)sPh + byt) = hi;
                *(ushort*)((char*)sPl + byt) = lo;
            }
    __syncthreads();

    // ---- PV: out 32x64 per wave = 2 m-frags x 4 n-frags, K=128
    f32x4 acc2[2][4];
#pragma unroll
    for (int m = 0; m < 2; ++m)
#pragma unroll
        for (int n = 0; n < 4; ++n) acc2[m][n] = (f32x4)0.0f;

#pragma unroll
    for (int ks = 0; ks < 4; ++ks) {
        const int kbyte = ks * 64 + (lane >> 4) * 16;
        bf16x8 ph[2], pl[2];
#pragma unroll
        for (int m = 0; m < 2; ++m) {
            const int r = i0 + m * 16 + l15;
            const int byt = r * 256 + (kbyte ^ ((r & 7) << 4));
            ph[m] = *(const bf16x8*)((const char*)sPh + byt);
            pl[m] = *(const bf16x8*)((const char*)sPl + byt);
        }
#pragma unroll
        for (int n = 0; n < 4; ++n) {
            const int d = n * 16 + l15;
            const int byt = d * 256 + (kbyte ^ ((d & 7) << 4));
            const bf16x8 vb = *(const bf16x8*)((const char*)sV + byt);
#pragma unroll
            for (int m = 0; m < 2; ++m) {
                acc2[m][n] = __builtin_amdgcn_mfma_f32_16x16x32_bf16(
                    ph[m], vb, acc2[m][n], 0, 0, 0);
                acc2[m][n] = __builtin_amdgcn_mfma_f32_16x16x32_bf16(
                    pl[m], vb, acc2[m][n], 0, 0, 0);
            }
        }
    }

    // ---- epilogue: attnT[b][c][E] split hi/lo
#pragma unroll
    for (int m = 0; m < 2; ++m)
#pragma unroll
        for (int n = 0; n < 4; ++n)
#pragma unroll
            for (int jj = 0; jj < 4; ++jj) {
                const int i = i0 + m * 16 + (lane >> 4) * 4 + jj;
                const int dcol = n * 16 + l15;
                ushort hi, lo;
                split_bf(acc2[m][n][jj], hi, lo);
                const size_t idx = ((size_t)b * C_ + i) * E_ + h * D_ + dcol;
                aTh[idx] = hi;
                aTl[idx] = lo;
            }
}

// ---------------------------------------------------------------------------
extern "C" void kernel_launch(void* const* d_in, const int* in_sizes, int n_in,
                              void* d_out, int out_size, void* d_ws, size_t ws_size,
                              hipStream_t stream) {
    const float* x        = (const float*)d_in[0];
    const float* wq       = (const float*)d_in[1];
    const float* wk       = (const float*)d_in[2];
    const float* wv       = (const float*)d_in[3];
    const float* wo       = (const float*)d_in[4];
    const float* dir_vec  = (const float*)d_in[5];
    const float* attn_b   = (const float*)d_in[6];
    const float* disp     = (const float*)d_in[7];
    const unsigned char* knn = (const unsigned char*)d_in[8];
    float* out = (float*)d_out;

    // workspace: 7 bf16 planes of BEC + weights + bias (~122 MB)
    char* ws = (char*)d_ws;
    size_t off = 0;
    ushort* qTh = (ushort*)(ws + off); off += BEC_ * 2;
    ushort* qTl = (ushort*)(ws + off); off += BEC_ * 2;
    ushort* kTh = (ushort*)(ws + off); off += BEC_ * 2;
    ushort* kTl = (ushort*)(ws + off); off += BEC_ * 2;
    ushort* vbuf = (ushort*)(ws + off); off += BEC_ * 2;
    ushort* xTh = (ushort*)(ws + off); off += BEC_ * 2;   // reused as attnT hi
    ushort* xTl = (ushort*)(ws + off); off += BEC_ * 2;   // reused as attnT lo
    ushort* wh  = (ushort*)(ws + off); off += (size_t)4 * E_ * E_ * 2;
    ushort* wl  = (ushort*)(ws + off); off += (size_t)4 * E_ * E_ * 2;
    float* combT = (float*)(ws + off); off += (size_t)H_ * C_ * C_ * sizeof(float);
    int* flag = (int*)(ws + off);

    detect_mask_kernel<<<1, 256, 0, stream>>>(knn, flag);
    bias_prep_kernel<<<dim3(C_, H_), 128, 0, stream>>>(dir_vec, attn_b, disp, knn,
                                                       flag, combT);
    wsplit_kernel<<<dim3(128, 4), 256, 0, stream>>>(wq, wk, wv, wo, wh, wl);
    xsplit_kernel<<<dim3(8, B_), 256, 0, stream>>>(x, xTh, xTl);

    const size_t WSZ = (size_t)E_ * E_;
    // q (trans), k (trans), v (natural hi) in one launch
    gemm_kernel<0><<<dim3(4, B_, 3), 256, 0, stream>>>(
        wh, wh + WSZ, wh + 2 * WSZ, wl, wl + WSZ, wl + 2 * WSZ,
        xTh, xTl, qTh, qTl, kTh, kTl, vbuf, nullptr);
    // MFMA attention -> attnT over xT buffers
    attn_mfma_kernel<<<dim3(B_, H_), 256, 0, stream>>>(
        qTh, qTl, kTh, kTl, vbuf, combT, xTh, xTl);
    // output projection -> d_out (fp32 + selu)
    gemm_kernel<1><<<dim3(4, B_, 1), 256, 0, stream>>>(
        wh + 3 * WSZ, wh + 3 * WSZ, wh + 3 * WSZ,
        wl + 3 * WSZ, wl + 3 * WSZ, wl + 3 * WSZ,
        xTh, xTl, nullptr, nullptr, nullptr, nullptr, nullptr, out);
}